// Round 5
// baseline (17693.915 us; speedup 1.0000x reference)
//
#include <hip/hip_runtime.h>
#include <hip/hip_bf16.h>
#include <stdint.h>

#define B_ 64
#define S_ 256
#define T_ 256
#define D_ 256
#define H_ 256
#define V_ 1000

__device__ __forceinline__ float blo(unsigned u){ return __uint_as_float(u << 16); }
__device__ __forceinline__ float bhi(unsigned u){ return __uint_as_float(u & 0xffff0000u); }
__device__ __forceinline__ float sigm(float x){ return 1.0f / (1.0f + __expf(-x)); }
__device__ __forceinline__ float tanhfast(float x){ float e = __expf(2.0f * x); return 1.0f - 2.0f / (e + 1.0f); }

__device__ __forceinline__ void cellupd(float a0, float a1, float a2, float a3, float& c, float& h){
  float cn = sigm(a1) * c + sigm(a0) * tanhfast(a2);
  c = cn;
  h = sigm(a3) * tanhfast(cn);
}

__device__ __forceinline__ float wredmax(float v){
  #pragma unroll
  for (int o = 32; o > 0; o >>= 1) v = fmaxf(v, __shfl_xor(v, o));
  return v;
}
__device__ __forceinline__ float wredsum(float v){
  #pragma unroll
  for (int o = 32; o > 0; o >>= 1) v += __shfl_xor(v, o);
  return v;
}

// fence-free device-coherent element access (sc0 sc1, no cache maintenance)
__device__ __forceinline__ void ast(float* p, float v){
  __hip_atomic_store(p, v, __ATOMIC_RELAXED, __HIP_MEMORY_SCOPE_AGENT);
}
__device__ __forceinline__ float ald(const float* p){
  return __hip_atomic_load(p, __ATOMIC_RELAXED, __HIP_MEMORY_SCOPE_AGENT);
}

// ---------------- dtype probe ----------------
__global__ void probe_kernel(const unsigned short* __restrict__ w, int* __restrict__ flag)
{
  int cnt = 0;
  for (int i = threadIdx.x; i < 4096; i += 64) {
    unsigned e = (w[i] >> 7) & 0xFFu;
    if (e >= 0xC0u) cnt++;
  }
  #pragma unroll
  for (int o = 32; o > 0; o >>= 1) cnt += __shfl_xor(cnt, o);
  if (threadIdx.x == 0) *flag = (cnt > 32) ? 1 : 0;
}

__device__ __forceinline__ float load_any(const void* src, int i, int isf32){
  return isf32 ? ((const float*)src)[i]
               : __uint_as_float(((unsigned)((const unsigned short*)src)[i]) << 16);
}

__global__ void conv_kernel(const void* __restrict__ src, float* __restrict__ dst, int n,
                            const int* __restrict__ flagp)
{
  int i = blockIdx.x * 256 + threadIdx.x;
  if (i >= n) return;
  dst[i] = load_any(src, i, *flagp);
}

__global__ void bias_kernel(const void* __restrict__ a, const void* __restrict__ bsrc,
                            float* __restrict__ dst, int n, const int* __restrict__ flagp)
{
  int i = blockIdx.x * 256 + threadIdx.x;
  if (i >= n) return;
  int f = *flagp;
  dst[i] = load_any(a, i, f) + load_any(bsrc, i, f);
}

// Swizzled bf16 weight layout for an (R x K) matrix:
//   swz[ (((R>>6)*(Kt>>3) + (k>>3))*64 + (R&63))*8 + (k&7) ] = bf16(W[r][k])
__global__ void swzb_kernel(const void* __restrict__ src, unsigned short* __restrict__ dst,
                            int R, int Ks, int Kt, int c0, int perm, const int* __restrict__ flagp)
{
  int i = blockIdx.x * 256 + threadIdx.x;
  if (i >= R * Ks) return;
  int r = i / Ks;
  int k = i - r * Ks;
  int kk = k + c0;
  int Rr = r;
  if (perm) {
    int g = r >> 8, j = r & 255;
    Rr = ((j >> 4) << 6) + (g << 4) + (j & 15);
  }
  float v = load_any(src, i, *flagp);
  __hip_bfloat16 bv = __float2bfloat16(v);
  dst[(((size_t)(Rr >> 6) * (size_t)(Kt >> 3) + (size_t)(kk >> 3)) * 64 + (Rr & 63)) * 8 + (kk & 7)] =
      *(unsigned short*)&bv;
}

// one full row r of an (R x K) swizzled bf16 matrix, x in LDS
template<int K>
__device__ __forceinline__ float dot1w(const unsigned short* __restrict__ w, int r,
                                       const float* __restrict__ xs)
{
  constexpr int KC = K >> 3;
  const uint4* __restrict__ p = (const uint4*)w + (size_t)(r >> 6) * KC * 64 + (r & 63);
  float a = 0.0f;
  #pragma unroll 4
  for (int kc = 0; kc < KC; ++kc) {
    const uint4 q = p[(size_t)kc * 64];
    const float4 x0 = *(const float4*)(xs + kc * 8);
    const float4 x1 = *(const float4*)(xs + kc * 8 + 4);
    a += blo(q.x)*x0.x + bhi(q.x)*x0.y + blo(q.y)*x0.z + bhi(q.y)*x0.w
       + blo(q.z)*x1.x + bhi(q.z)*x1.y + blo(q.w)*x1.z + bhi(q.w)*x1.w;
  }
  return a;
}

// Split-K 4-gate partial dot (encoders): rows {g*256+j}, K-slice q.
template<int KC, int SL>
__device__ __forceinline__ void dot4s(const unsigned short* __restrict__ w, int j, int q,
                                      const float* __restrict__ xsl, float out4[4])
{
  const int lane = j & 63, wq = j >> 6;
  const uint4* __restrict__ p0 = (const uint4*)w + ((size_t)(wq     ) * KC + q * SL) * 64 + lane;
  const uint4* __restrict__ p1 = (const uint4*)w + ((size_t)(wq + 4 ) * KC + q * SL) * 64 + lane;
  const uint4* __restrict__ p2 = (const uint4*)w + ((size_t)(wq + 8 ) * KC + q * SL) * 64 + lane;
  const uint4* __restrict__ p3 = (const uint4*)w + ((size_t)(wq + 12) * KC + q * SL) * 64 + lane;
  float a0 = 0.0f, a1 = 0.0f, a2 = 0.0f, a3 = 0.0f;
  #pragma unroll 4
  for (int kc = 0; kc < SL; ++kc) {
    const float4 x0 = *(const float4*)(xsl + kc * 8);
    const float4 x1 = *(const float4*)(xsl + kc * 8 + 4);
    uint4 qq;
    qq = p0[(size_t)kc * 64];
    a0 += blo(qq.x)*x0.x + bhi(qq.x)*x0.y + blo(qq.y)*x0.z + bhi(qq.y)*x0.w
        + blo(qq.z)*x1.x + bhi(qq.z)*x1.y + blo(qq.w)*x1.z + bhi(qq.w)*x1.w;
    qq = p1[(size_t)kc * 64];
    a1 += blo(qq.x)*x0.x + bhi(qq.x)*x0.y + blo(qq.y)*x0.z + bhi(qq.y)*x0.w
        + blo(qq.z)*x1.x + bhi(qq.z)*x1.y + blo(qq.w)*x1.z + bhi(qq.w)*x1.w;
    qq = p2[(size_t)kc * 64];
    a2 += blo(qq.x)*x0.x + bhi(qq.x)*x0.y + blo(qq.y)*x0.z + bhi(qq.y)*x0.w
        + blo(qq.z)*x1.x + bhi(qq.z)*x1.y + blo(qq.w)*x1.z + bhi(qq.w)*x1.w;
    qq = p3[(size_t)kc * 64];
    a3 += blo(qq.x)*x0.x + bhi(qq.x)*x0.y + blo(qq.y)*x0.z + bhi(qq.y)*x0.w
        + blo(qq.z)*x1.x + bhi(qq.z)*x1.y + blo(qq.w)*x1.z + bhi(qq.w)*x1.w;
  }
  out4[0] = a0; out4[1] = a1; out4[2] = a2; out4[3] = a3;
}

// ---------------- encoder (unchanged) ----------------
__global__ __launch_bounds__(1024, 1) void enc0_kernel(
    const int* __restrict__ src, const float* __restrict__ emb_f,
    const unsigned short* __restrict__ wF, const unsigned short* __restrict__ wB,
    const float* __restrict__ bF, const float* __restrict__ bB,
    float* __restrict__ f0, float* __restrict__ b0)
{
  const int blk = blockIdx.x, dir = blk >> 6, b = blk & 63, tid = threadIdx.x;
  const unsigned short* w = dir ? wB : wF;
  const float* bi = dir ? bB : bF;
  float* outp = dir ? b0 : f0;
  __shared__ __align__(16) float xs[512];
  __shared__ __align__(16) float work4[4096];
  const int q = tid >> 8, j = tid & 255;
  float bias_g[4];
  if (tid < 256) {
    #pragma unroll
    for (int g = 0; g < 4; ++g) bias_g[g] = bi[g * 256 + tid];
    xs[256 + tid] = 0.0f;
  }
  float c = 0.0f, h = 0.0f;
  const size_t bS = (size_t)b * S_;
  for (int t = 0; t < S_; ++t) {
    const int tp = dir ? (S_ - 1 - t) : t;
    const int tok = src[bS + tp];
    if (tid < 256) xs[tid] = emb_f[(size_t)tok * D_ + tid];
    __syncthreads();
    float o4[4];
    dot4s<64, 16>(w, j, q, xs + q * 128, o4);
    #pragma unroll
    for (int g = 0; g < 4; ++g) work4[(g * 4 + q) * 256 + j] = o4[g];
    __syncthreads();
    if (tid < 256) {
      float gv[4];
      #pragma unroll
      for (int g = 0; g < 4; ++g)
        gv[g] = work4[(g*4+0)*256 + tid] + work4[(g*4+1)*256 + tid]
              + work4[(g*4+2)*256 + tid] + work4[(g*4+3)*256 + tid] + bias_g[g];
      cellupd(gv[0], gv[1], gv[2], gv[3], c, h);
      xs[256 + tid] = h;
      outp[(bS + tp) * H_ + tid] = h;
    }
    __syncthreads();
  }
}

__global__ __launch_bounds__(1024, 1) void enc1_kernel(
    const float* __restrict__ f0, const float* __restrict__ b0,
    const unsigned short* __restrict__ wF, const unsigned short* __restrict__ wB,
    const float* __restrict__ bF, const float* __restrict__ bB,
    float* __restrict__ enc_out, float* __restrict__ hcbuf)
{
  const int blk = blockIdx.x, dir = blk >> 6, b = blk & 63, tid = threadIdx.x;
  const unsigned short* w = dir ? wB : wF;
  const float* bi = dir ? bB : bF;
  __shared__ __align__(16) float xs[768];
  __shared__ __align__(16) float work4[4096];
  const int q = tid >> 8, j = tid & 255;
  float bias_g[4];
  if (tid < 256) {
    #pragma unroll
    for (int g = 0; g < 4; ++g) bias_g[g] = bi[g * 256 + tid];
    xs[512 + tid] = 0.0f;
  }
  float c = 0.0f, h = 0.0f;
  const size_t bS = (size_t)b * S_;
  for (int t = 0; t < S_; ++t) {
    const int tp = dir ? (S_ - 1 - t) : t;
    const size_t row = (bS + tp) * (size_t)H_;
    if (tid < 512) {
      const int jj = tid & 255;
      xs[tid] = (tid < 256) ? f0[row + jj] : b0[row + jj];
    }
    __syncthreads();
    float o4[4];
    dot4s<96, 24>(w, j, q, xs + q * 192, o4);
    #pragma unroll
    for (int g = 0; g < 4; ++g) work4[(g * 4 + q) * 256 + j] = o4[g];
    __syncthreads();
    if (tid < 256) {
      float gv[4];
      #pragma unroll
      for (int g = 0; g < 4; ++g)
        gv[g] = work4[(g*4+0)*256 + tid] + work4[(g*4+1)*256 + tid]
              + work4[(g*4+2)*256 + tid] + work4[(g*4+3)*256 + tid] + bias_g[g];
      cellupd(gv[0], gv[1], gv[2], gv[3], c, h);
      xs[512 + tid] = h;
      enc_out[(bS + tp) * 512 + dir * 256 + tid] = h;
    }
    __syncthreads();
  }
  if (tid < 256) {
    const int BH = B_ * H_;
    float* hout = hcbuf + (dir ? 2 * BH : 0);
    hout[(size_t)b * H_ + tid]      = h;
    hout[BH + (size_t)b * H_ + tid] = c;
  }
}

// proj (unchanged)
__global__ __launch_bounds__(256) void proj_kernel(
    const float* __restrict__ enc_out, const float* __restrict__ hcbuf,
    const unsigned short* __restrict__ wenc_s,
    const unsigned short* __restrict__ hpw_s, const unsigned short* __restrict__ cpw_s,
    const float* __restrict__ hpb_f, const float* __restrict__ cpb_f,
    float* __restrict__ epT, float* __restrict__ h0c0)
{
  __shared__ __align__(16) float xs[16 * 512];
  const int blk = blockIdx.x, tid = threadIdx.x;
  if (blk < 1024) {
    const int b = blk >> 4, s0 = (blk & 15) * 16;
    const float* srcp = enc_out + ((size_t)b * S_ + s0) * 512;
    for (int i = tid; i < 16 * 512; i += 256) xs[i] = srcp[i];
    __syncthreads();
    float acc[16];
    #pragma unroll
    for (int r = 0; r < 16; ++r) acc[r] = 0.0f;
    const uint4* p = (const uint4*)wenc_s + (size_t)(tid >> 6) * 64 * 64 + (tid & 63);
    for (int kc = 0; kc < 64; ++kc) {
      const uint4 q = p[(size_t)kc * 64];
      const float w0=blo(q.x), w1=bhi(q.x), w2=blo(q.y), w3=bhi(q.y),
                  w4=blo(q.z), w5=bhi(q.z), w6=blo(q.w), w7=bhi(q.w);
      #pragma unroll
      for (int r = 0; r < 16; ++r) {
        const float4 x0 = *(const float4*)(xs + r * 512 + kc * 8);
        const float4 x1 = *(const float4*)(xs + r * 512 + kc * 8 + 4);
        acc[r] += w0*x0.x + w1*x0.y + w2*x0.z + w3*x0.w + w4*x1.x + w5*x1.y + w6*x1.z + w7*x1.w;
      }
    }
    float* dst = epT + ((size_t)b * S_ + (size_t)tid) * 256 + s0;
    #pragma unroll
    for (int r = 0; r < 16; ++r) dst[r] = acc[r];
  } else {
    const int b = blk - 1024;
    const int BH = B_ * H_;
    xs[tid]        = hcbuf[(size_t)b * H_ + tid];
    xs[256 + tid]  = hcbuf[2 * BH + (size_t)b * H_ + tid];
    xs[512 + tid]  = hcbuf[BH + (size_t)b * H_ + tid];
    xs[768 + tid]  = hcbuf[3 * BH + (size_t)b * H_ + tid];
    __syncthreads();
    const float hv = dot1w<512>(hpw_s, tid, xs)       + hpb_f[tid];
    const float cv = dot1w<512>(cpw_s, tid, xs + 512) + cpb_f[tid];
    h0c0[(size_t)b * H_ + tid]              = tanhfast(hv);
    h0c0[(size_t)BH + (size_t)b * H_ + tid] = tanhfast(cv);
  }
}

// ---------------- gemb: precompute Wih[:, :256] @ emb[tok] for all 1000 tokens ----------------
__global__ __launch_bounds__(256) void gemb_kernel(
    const float* __restrict__ emb_f, const unsigned short* __restrict__ d0p,
    float* __restrict__ gemb)
{
  __shared__ __align__(16) float xs[16 * 256];
  const int blk = blockIdx.x, tg = blk >> 2, cg = blk & 3, tid = threadIdx.x;
  for (int i = tid; i < 16 * 256; i += 256) {
    const int tk = tg * 16 + (i >> 8);
    xs[i] = (tk < V_) ? emb_f[(size_t)tk * 256 + (i & 255)] : 0.0f;
  }
  __syncthreads();
  const int r = cg * 256 + tid;   // gate-row 0..1023
  const uint4* p = (const uint4*)d0p + (size_t)(r >> 6) * 128 * 64 + (r & 63);
  float acc[16];
  #pragma unroll
  for (int ti = 0; ti < 16; ++ti) acc[ti] = 0.0f;
  for (int kc = 0; kc < 32; ++kc) {
    const uint4 q = p[(size_t)kc * 64];
    const float w0=blo(q.x), w1=bhi(q.x), w2=blo(q.y), w3=bhi(q.y),
                w4=blo(q.z), w5=bhi(q.z), w6=blo(q.w), w7=bhi(q.w);
    #pragma unroll
    for (int ti = 0; ti < 16; ++ti) {
      const float4 x0 = *(const float4*)(xs + ti * 256 + kc * 8);
      const float4 x1 = *(const float4*)(xs + ti * 256 + kc * 8 + 4);
      acc[ti] += w0*x0.x + w1*x0.y + w2*x0.z + w3*x0.w + w4*x1.x + w5*x1.y + w6*x1.z + w7*x1.w;
    }
  }
  #pragma unroll
  for (int ti = 0; ti < 16; ++ti) {
    const int tk = tg * 16 + ti;
    if (tk < V_) gemb[(size_t)tk * 1024 + r] = acc[ti];
  }
}

__global__ void zero_cnt_kernel(int* __restrict__ cnt)
{
  cnt[threadIdx.x] = 0;
}

// ---------------- fused decoder v5: 256 blocks, Bk = b*4 + k ----------------
// k-slices of a batch spread across 4 XCDs -> per-XCD weight set ~0.7 MB (L2-resident).
// j-sliced attention query (wdec read 4x smaller); partial energies summed via esc[b][k][s].
// LDS-resident epT[s][j-slice] + enc_out[d-slice][s]. Fence-free relaxed-atomic exchange.
__global__ __launch_bounds__(1024, 1) void dec_fused_kernel(
    const int* __restrict__ src, const int* __restrict__ tgt,
    const float* __restrict__ h0c0,
    const float* __restrict__ epT, const float* __restrict__ enc_out,
    const float* __restrict__ gemb,
    const unsigned short* __restrict__ wdec_s,
    const unsigned short* __restrict__ d0p, const unsigned short* __restrict__ d1p,
    const float* __restrict__ d0b, const float* __restrict__ d1b,
    const float* __restrict__ attv_f,
    float* __restrict__ dec_h,
    float* __restrict__ esc, float* __restrict__ ctxg,
    float* __restrict__ hl0g, float* __restrict__ hl1g,
    int* __restrict__ cnt)
{
  const int Bk = blockIdx.x, b = Bk >> 2, k = Bk & 3, tid = threadIdx.x;
  const int j64 = k * 64;

  __shared__ __align__(16) float epl[256 * 65];            // epT[s][j-slice], pitch 65 (odd words)
  __shared__ __align__(16) unsigned short eol[128 * 264];  // enc_out[d-slice][s], bf16
  __shared__ __align__(16) float work[1024];
  __shared__ __align__(16) float xs0[768];        // [ctx(512) | hl0_prev(256)]
  __shared__ __align__(16) float hl1s[256];
  __shared__ __align__(16) float hl0n[256];
  __shared__ __align__(16) float qloc[64];
  __shared__ __align__(16) float vv[64];
  __shared__ __align__(16) float msk[256];
  __shared__ __align__(16) float wsm[256];
  __shared__ __align__(16) float cl0s[64];
  __shared__ __align__(16) float cl1s[64];
  __shared__ float red[16];

  const float* epb = epT + (size_t)b * (S_ * 256);
  const float* eob = enc_out + (size_t)b * (S_ * 512);

  // ---- prologue: stage slices into LDS (one-time) ----
  for (int i = tid; i < 256 * 64; i += 1024) {
    const int s = i & 255, jj = i >> 8;
    epl[s * 65 + jj] = epb[(size_t)(j64 + jj) * 256 + s];
  }
  for (int i = tid; i < 128 * 256; i += 1024) {
    const int dl = i & 127, s = i >> 7;
    __hip_bfloat16 bv = __float2bfloat16(eob[(size_t)s * 512 + k * 128 + dl]);
    eol[dl * 264 + s] = *(unsigned short*)&bv;
  }
  if (tid < 256) {
    msk[tid] = (src[b * 256 + tid] == 0) ? -1e30f : 0.0f;
    const float h0 = h0c0[b * 256 + tid];
    hl1s[tid] = h0;
    xs0[512 + tid] = h0;
  }
  float b0r[4], b1r[4];
  if (tid < 64) {
    vv[tid] = attv_f[j64 + tid];
    const float c0 = h0c0[B_ * H_ + b * 256 + j64 + tid];
    cl0s[tid] = c0; cl1s[tid] = c0;
    #pragma unroll
    for (int g = 0; g < 4; ++g) {
      b0r[g] = d0b[g * 256 + j64 + tid];
      b1r[g] = d1b[g * 256 + j64 + tid];
    }
  }
  __syncthreads();

  int syncno = 0;
  // fence-free barrier among the 4 blocks of batch b
#define GSYNC() do {                                                                    \
    ++syncno;                                                                           \
    __syncthreads();  /* drains vmcnt(0): all sc1 data stores acked at coherence pt */  \
    if (tid == 0) {                                                                     \
      __hip_atomic_fetch_add(&cnt[b], 1, __ATOMIC_RELAXED, __HIP_MEMORY_SCOPE_AGENT);   \
      while (__hip_atomic_load(&cnt[b], __ATOMIC_RELAXED, __HIP_MEMORY_SCOPE_AGENT)     \
             < 4 * syncno)                                                              \
        __builtin_amdgcn_s_sleep(2);                                                    \
    }                                                                                   \
    __syncthreads();                                                                    \
    asm volatile("" ::: "memory");                                                      \
  } while (0)

  for (int t = 0; t < T_; ++t) {
    // prefetch the token gate-table slice (consumed at E-tail, hides L2/L3 latency)
    float gpre[4];
    if (tid < 64) {
      const float* ge = gemb + (size_t)tgt[b * 257 + t] * 1024;
      #pragma unroll
      for (int g = 0; g < 4; ++g) gpre[g] = ge[g * 256 + j64 + tid];
    }

    // ---- A: qloc = Wdec[j-slice] @ hl1s (reads 32 KB of wdec) ----
    {
      const int jj = tid & 63, q16 = tid >> 6;
      const uint4* p = (const uint4*)wdec_s + ((size_t)k * 32 + q16 * 2) * 64 + jj;
      const float* xsl = hl1s + q16 * 16;
      const uint4 w0 = p[0], w1 = p[64];
      const float4 xa = *(const float4*)(xsl);
      const float4 xb = *(const float4*)(xsl + 4);
      const float4 xc = *(const float4*)(xsl + 8);
      const float4 xd = *(const float4*)(xsl + 12);
      const float a =
          blo(w0.x)*xa.x + bhi(w0.x)*xa.y + blo(w0.y)*xa.z + bhi(w0.y)*xa.w
        + blo(w0.z)*xb.x + bhi(w0.z)*xb.y + blo(w0.w)*xb.z + bhi(w0.w)*xb.w
        + blo(w1.x)*xc.x + bhi(w1.x)*xc.y + blo(w1.y)*xc.z + bhi(w1.y)*xc.w
        + blo(w1.z)*xd.x + bhi(w1.z)*xd.y + blo(w1.w)*xd.z + bhi(w1.w)*xd.w;
      work[q16 * 64 + jj] = a;
    }
    __syncthreads();
    if (tid < 64) {
      float q = 0.0f;
      #pragma unroll
      for (int i = 0; i < 16; ++i) q += work[i * 64 + tid];
      qloc[tid] = q;
    }
    __syncthreads();

    // ---- B: partial energies over this block's j-slice for ALL 256 s ----
    {
      const int s = tid & 255, jq = tid >> 8;
      const float* ep = epl + s * 65 + jq * 16;
      const float* qv = qloc + jq * 16;
      const float* vp = vv + jq * 16;
      float a = 0.0f;
      #pragma unroll
      for (int i = 0; i < 16; ++i)
        a += vp[i] * tanhfast(ep[i] + qv[i]);
      work[jq * 256 + s] = a;
    }
    __syncthreads();
    if (tid < 256)
      ast(&esc[b * 1024 + k * 256 + tid],
          work[tid] + work[256 + tid] + work[512 + tid] + work[768 + tid]);
    GSYNC();  // sync1: all partial energies visible

    // ---- C (replicated): sum partials + softmax ----
    {
      float e = -1e30f;
      if (tid < 256) {
        const float* eb = esc + b * 1024;
        e = ald(&eb[tid]) + ald(&eb[256 + tid]) + ald(&eb[512 + tid]) + ald(&eb[768 + tid])
          + msk[tid];
      }
      const float m0 = wredmax(e);
      if (tid < 256 && (tid & 63) == 0) red[tid >> 6] = m0;
      __syncthreads();
      const float m = fmaxf(fmaxf(red[0], red[1]), fmaxf(red[2], red[3]));
      const float pe = (tid < 256) ? __expf(e - m) : 0.0f;
      const float ss = wredsum(pe);
      if (tid < 256 && (tid & 63) == 0) red[4 + (tid >> 6)] = ss;
      __syncthreads();
      const float inv = 1.0f / ((red[4] + red[5]) + (red[6] + red[7]));
      if (tid < 256) wsm[tid] = pe * inv;
    }
    __syncthreads();

    // ---- D: ctx d-slice [128k, 128k+128) from LDS enc_out slice ----
    {
      const int dq = tid & 127, sg = tid >> 7;    // 8 s-groups x 128 d
      const uint4* er = (const uint4*)(eol + dq * 264 + sg * 32);
      const float* wp = wsm + sg * 32;
      float a = 0.0f;
      #pragma unroll
      for (int i4 = 0; i4 < 4; ++i4) {
        const uint4 q = er[i4];
        const float* w8 = wp + i4 * 8;
        a += blo(q.x)*w8[0] + bhi(q.x)*w8[1] + blo(q.y)*w8[2] + bhi(q.y)*w8[3]
           + blo(q.z)*w8[4] + bhi(q.z)*w8[5] + blo(q.w)*w8[6] + bhi(q.w)*w8[7];
      }
      work[sg * 128 + dq] = a;
    }
    __syncthreads();
    if (tid < 128) {
      float a = 0.0f;
      #pragma unroll
      for (int g = 0; g < 8; ++g) a += work[g * 128 + tid];
      ast(&ctxg[b * 512 + k * 128 + tid], a);
    }
    GSYNC();  // sync2: full ctx visible
    if (tid < 512) xs0[tid] = ald(&ctxg[b * 512 + tid]);
    __syncthreads();

    // ---- E: cell0 gate rows {g*256 + j64 + jj}, K-cols 256..1023 ----
    {
      const int lr = tid & 255, q4 = tid >> 8;
      const int g = lr >> 6, jj = lr & 63;
      const uint4* p = (const uint4*)d0p + ((size_t)(g * 4 + k) * 128 + 32 + q4 * 24) * 64 + jj;
      const float* xsl = xs0 + q4 * 192;
      float a = 0.0f;
      #pragma unroll 8
      for (int kc = 0; kc < 24; ++kc) {
        const uint4 w = p[(size_t)kc * 64];
        const float4 x0 = *(const float4*)(xsl + kc * 8);
        const float4 x1 = *(const float4*)(xsl + kc * 8 + 4);
        a += blo(w.x)*x0.x + bhi(w.x)*x0.y + blo(w.y)*x0.z + bhi(w.y)*x0.w
           + blo(w.z)*x1.x + bhi(w.z)*x1.y + blo(w.w)*x1.z + bhi(w.w)*x1.w;
      }
      work[q4 * 256 + lr] = a;
    }
    __syncthreads();
    if (tid < 64) {
      float gv[4];
      #pragma unroll
      for (int g = 0; g < 4; ++g) {
        const int lr = g * 64 + tid;
        gv[g] = work[lr] + work[256 + lr] + work[512 + lr] + work[768 + lr]
              + b0r[g] + gpre[g];
      }
      float c = cl0s[tid], h;
      cellupd(gv[0], gv[1], gv[2], gv[3], c, h);
      cl0s[tid] = c;
      ast(&hl0g[b * 256 + j64 + tid], h);
    }
    GSYNC();  // sync3: full hl0(t) visible
    if (tid < 256) {
      const float hv = ald(&hl0g[b * 256 + tid]);
      hl0n[tid] = hv;
      xs0[512 + tid] = hv;   // becomes hl0_prev for next step's E
    }
    __syncthreads();

    // ---- F: cell1 gate rows, K=512 = [hl0n | hl1s] ----
    {
      const int lr = tid & 255, q4 = tid >> 8;
      const int g = lr >> 6, jj = lr & 63;
      const uint4* p = (const uint4*)d1p + ((size_t)(g * 4 + k) * 64 + q4 * 16) * 64 + jj;
      const float* xsl = (q4 < 2) ? (hl0n + q4 * 128) : (hl1s + (q4 - 2) * 128);
      float a = 0.0f;
      #pragma unroll 8
      for (int kc = 0; kc < 16; ++kc) {
        const uint4 w = p[(size_t)kc * 64];
        const float4 x0 = *(const float4*)(xsl + kc * 8);
        const float4 x1 = *(const float4*)(xsl + kc * 8 + 4);
        a += blo(w.x)*x0.x + bhi(w.x)*x0.y + blo(w.y)*x0.z + bhi(w.y)*x0.w
           + blo(w.z)*x1.x + bhi(w.z)*x1.y + blo(w.w)*x1.z + bhi(w.w)*x1.w;
      }
      work[q4 * 256 + lr] = a;
    }
    __syncthreads();
    if (tid < 64) {
      float gv[4];
      #pragma unroll
      for (int g = 0; g < 4; ++g) {
        const int lr = g * 64 + tid;
        gv[g] = work[lr] + work[256 + lr] + work[512 + lr] + work[768 + lr] + b1r[g];
      }
      float c = cl1s[tid], h;
      cellupd(gv[0], gv[1], gv[2], gv[3], c, h);
      cl1s[tid] = c;
      ast(&hl1g[b * 256 + j64 + tid], h);
      dec_h[((size_t)b * T_ + t) * H_ + j64 + tid] = h;
    }
    GSYNC();  // sync4: full hl1(t) visible
    if (tid < 256) hl1s[tid] = ald(&hl1g[b * 256 + tid]);
    __syncthreads();
  }
#undef GSYNC
}

// out (unchanged)
__global__ __launch_bounds__(256) void out_kernel(
    const float* __restrict__ dec_h, const unsigned short* __restrict__ emb_s,
    void* __restrict__ out, const int* __restrict__ flagp)
{
  __shared__ __align__(16) float hs[16 * 256];
  const int blk = blockIdx.x, tid = threadIdx.x;
  const int isf32 = *flagp;
  const float* srcp = dec_h + (size_t)blk * (16 * 256);
  for (int i = tid; i < 16 * 256; i += 256) hs[i] = srcp[i];
  __syncthreads();
  #pragma unroll
  for (int vi = 0; vi < 4; ++vi) {
    const int v = tid + vi * 256;
    if (v < V_) {
      const uint4* p = (const uint4*)emb_s + (size_t)(v >> 6) * 32 * 64 + (v & 63);
      float acc[16];
      #pragma unroll
      for (int r = 0; r < 16; ++r) acc[r] = 0.0f;
      for (int kc = 0; kc < 32; ++kc) {
        const uint4 q = p[(size_t)kc * 64];
        const float w0=blo(q.x), w1=bhi(q.x), w2=blo(q.y), w3=bhi(q.y),
                    w4=blo(q.z), w5=bhi(q.z), w6=blo(q.w), w7=bhi(q.w);
        #pragma unroll
        for (int r = 0; r < 16; ++r) {
          const float4 x0 = *(const float4*)(hs + r * 256 + kc * 8);
          const float4 x1 = *(const float4*)(hs + r * 256 + kc * 8 + 4);
          acc[r] += w0*x0.x + w1*x0.y + w2*x0.z + w3*x0.w + w4*x1.x + w5*x1.y + w6*x1.z + w7*x1.w;
        }
      }
      const size_t rowbase = (size_t)blk * 16;
      if (isf32) {
        float* o = (float*)out;
        #pragma unroll
        for (int r = 0; r < 16; ++r) o[(rowbase + r) * V_ + v] = acc[r];
      } else {
        __hip_bfloat16* o = (__hip_bfloat16*)out;
        #pragma unroll
        for (int r = 0; r < 16; ++r) o[(rowbase + r) * V_ + v] = __float2bfloat16(acc[r]);
      }
    }
  }
}

extern "C" void kernel_launch(void* const* d_in, const int* in_sizes, int n_in,
                              void* d_out, int out_size, void* d_ws, size_t ws_size,
                              hipStream_t stream)
{
  (void)in_sizes; (void)n_in; (void)out_size; (void)ws_size;
  const int* src = (const int*)d_in[0];
  const int* tgt = (const int*)d_in[1];

  char* base = (char*)d_ws;
  int* flag = (int*)base;
  float* ws = (float*)(base + 256);
  size_t off = 0;
  float* f0      = ws + off; off += (size_t)B_ * S_ * H_;
  float* b0      = ws + off; off += (size_t)B_ * S_ * H_;
  float* enc_out = ws + off; off += (size_t)B_ * S_ * 2 * H_;
  float* hcbuf   = ws + off; off += 4 * (size_t)B_ * H_;
  float* h0c0    = ws + off; off += 2 * (size_t)B_ * H_;
  float* emb_f   = ws + off; off += (size_t)V_ * D_;
  float* gemb    = ws + off; off += (size_t)V_ * 1024;
  float* esc     = ws + off; off += (size_t)B_ * S_ * 4;
  float* ctxg    = ws + off; off += (size_t)B_ * 512;
  float* hl0g    = ws + off; off += (size_t)B_ * H_;
  float* hl1g    = ws + off; off += (size_t)B_ * H_;
  int*   cntp    = (int*)(ws + off); off += 64;
  float* e0f_b   = ws + off; off += 1024;
  float* e0b_b   = ws + off; off += 1024;
  float* e1f_b   = ws + off; off += 1024;
  float* e1b_b   = ws + off; off += 1024;
  float* d0_b    = ws + off; off += 1024;
  float* d1_b    = ws + off; off += 1024;
  float* hpb_f   = ws + off; off += 256;
  float* cpb_f   = ws + off; off += 256;
  float* attv_f  = ws + off; off += 256;
  unsigned short* us = (unsigned short*)(ws + off);
  size_t uo = 0;
  unsigned short* e0f_s  = us + uo; uo += (size_t)1024 * 512;
  unsigned short* e0b_s  = us + uo; uo += (size_t)1024 * 512;
  unsigned short* e1f_s  = us + uo; uo += (size_t)1024 * 768;
  unsigned short* e1b_s  = us + uo; uo += (size_t)1024 * 768;
  unsigned short* d0p_s  = us + uo; uo += (size_t)1024 * 1024;
  unsigned short* d1p_s  = us + uo; uo += (size_t)1024 * 512;
  unsigned short* wdec_s = us + uo; uo += (size_t)256 * 256;
  unsigned short* wenc_s = us + uo; uo += (size_t)256 * 512;
  unsigned short* hpw_s  = us + uo; uo += (size_t)256 * 512;
  unsigned short* cpw_s  = us + uo; uo += (size_t)256 * 512;
  unsigned short* emb_s  = us + uo; uo += (size_t)1024 * 256;
  float* dec_h = f0;
  float* epT   = b0;

  hipLaunchKernelGGL(probe_kernel, dim3(1), dim3(64), 0, stream,
                     (const unsigned short*)d_in[3], flag);

  auto swz = [&](int idx, unsigned short* dst, int R, int Ks, int Kt, int c0, int perm){
    const int n = R * Ks;
    hipLaunchKernelGGL(swzb_kernel, dim3((n + 255) / 256), dim3(256), 0, stream,
                       d_in[idx], dst, R, Ks, Kt, c0, perm, flag);
  };
  auto bias2 = [&](int ia, int ib, float* dst, int n){
    hipLaunchKernelGGL(bias_kernel, dim3((n + 255) / 256), dim3(256), 0, stream,
                       d_in[ia], d_in[ib], dst, n, flag);
  };

  hipLaunchKernelGGL(conv_kernel, dim3((V_ * D_ + 255) / 256), dim3(256), 0, stream,
                     d_in[2], emb_f, V_ * D_, flag);
  hipLaunchKernelGGL(conv_kernel, dim3(1), dim3(256), 0, stream, d_in[28], hpb_f, 256, flag);
  hipLaunchKernelGGL(conv_kernel, dim3(1), dim3(256), 0, stream, d_in[30], cpb_f, 256, flag);
  hipLaunchKernelGGL(conv_kernel, dim3(1), dim3(256), 0, stream, d_in[33], attv_f, 256, flag);
  bias2(5, 6, e0f_b, 1024);   bias2(9, 10, e0b_b, 1024);
  bias2(13, 14, e1f_b, 1024); bias2(17, 18, e1b_b, 1024);
  bias2(21, 22, d0_b, 1024);  bias2(25, 26, d1_b, 1024);
  swz(3,  e0f_s, 1024, 256, 512, 0, 0);   swz(4,  e0f_s, 1024, 256, 512, 256, 0);
  swz(7,  e0b_s, 1024, 256, 512, 0, 0);   swz(8,  e0b_s, 1024, 256, 512, 256, 0);
  swz(11, e1f_s, 1024, 512, 768, 0, 0);   swz(12, e1f_s, 1024, 256, 768, 512, 0);
  swz(15, e1b_s, 1024, 512, 768, 0, 0);   swz(16, e1b_s, 1024, 256, 768, 512, 0);
  swz(19, d0p_s, 1024, 768, 1024, 0, 0);  swz(20, d0p_s, 1024, 256, 1024, 768, 0);
  swz(23, d1p_s, 1024, 256, 512, 0, 0);   swz(24, d1p_s, 1024, 256, 512, 256, 0);
  swz(32, wdec_s, 256, 256, 256, 0, 0);
  swz(31, wenc_s, 256, 512, 512, 0, 0);
  swz(27, hpw_s, 256, 512, 512, 0, 0);
  swz(29, cpw_s, 256, 512, 512, 0, 0);
  swz(2,  emb_s, 1000, 256, 256, 0, 0);

  // token-gate table (needs emb_f + d0p_s)
  hipLaunchKernelGGL(gemb_kernel, dim3(252), dim3(256), 0, stream, emb_f, d0p_s, gemb);

  hipLaunchKernelGGL(enc0_kernel, dim3(128), dim3(1024), 0, stream,
                     src, emb_f, e0f_s, e0b_s, e0f_b, e0b_b, f0, b0);
  hipLaunchKernelGGL(enc1_kernel, dim3(128), dim3(1024), 0, stream,
                     f0, b0, e1f_s, e1b_s, e1f_b, e1b_b, enc_out, hcbuf);
  hipLaunchKernelGGL(proj_kernel, dim3(1088), dim3(256), 0, stream,
                     enc_out, hcbuf, wenc_s, hpw_s, cpw_s, hpb_f, cpb_f, epT, h0c0);

  hipLaunchKernelGGL(zero_cnt_kernel, dim3(1), dim3(64), 0, stream, cntp);

  {
    const int* srcp_ = src; const int* tgtp_ = tgt;
    const float* h0c0_ = h0c0; const float* epT_ = epT; const float* eo_ = enc_out;
    const float* gemb_ = gemb;
    const unsigned short* wdec_ = wdec_s;
    const unsigned short* d0p_ = d0p_s; const unsigned short* d1p_ = d1p_s;
    const float* d0b_ = d0_b; const float* d1b_ = d1_b; const float* attv_ = attv_f;
    float* dech_ = dec_h; float* esc_ = esc; float* ctxg_ = ctxg;
    float* hl0g_ = hl0g; float* hl1g_ = hl1g; int* cnt_ = cntp;
    void* kargs[] = {
      (void*)&srcp_, (void*)&tgtp_, (void*)&h0c0_, (void*)&epT_, (void*)&eo_,
      (void*)&gemb_, (void*)&wdec_, (void*)&d0p_, (void*)&d1p_,
      (void*)&d0b_, (void*)&d1b_, (void*)&attv_,
      (void*)&dech_, (void*)&esc_, (void*)&ctxg_, (void*)&hl0g_, (void*)&hl1g_, (void*)&cnt_
    };
    hipError_t e = hipLaunchCooperativeKernel((const void*)dec_fused_kernel,
                                              dim3(256), dim3(1024), kargs, 0, stream);
    if (e != hipSuccess) {
      // fallback: plain launch (256 blocks, 1 block/CU, all co-resident)
      hipLaunchKernelGGL(dec_fused_kernel, dim3(256), dim3(1024), 0, stream,
                         srcp_, tgtp_, h0c0_, epT_, eo_, gemb_, wdec_, d0p_, d1p_,
                         d0b_, d1b_, attv_, dech_, esc_, ctxg_, hl0g_, hl1g_, cnt_);
    }
  }

  hipLaunchKernelGGL(out_kernel, dim3(1024), dim3(256), 0, stream,
                     dec_h, emb_s, d_out, flag);
}

// Round 7
// 13612.807 us; speedup vs baseline: 1.2998x; 1.2998x over previous
//
#include <hip/hip_runtime.h>
#include <hip/hip_bf16.h>
#include <stdint.h>

#define B_ 64
#define S_ 256
#define T_ 256
#define D_ 256
#define H_ 256
#define V_ 1000

__device__ __forceinline__ float blo(unsigned u){ return __uint_as_float(u << 16); }
__device__ __forceinline__ float bhi(unsigned u){ return __uint_as_float(u & 0xffff0000u); }
__device__ __forceinline__ float sigm(float x){ return 1.0f / (1.0f + __expf(-x)); }
__device__ __forceinline__ float tanhfast(float x){ float e = __expf(2.0f * x); return 1.0f - 2.0f / (e + 1.0f); }

__device__ __forceinline__ void cellupd(float a0, float a1, float a2, float a3, float& c, float& h){
  float cn = sigm(a1) * c + sigm(a0) * tanhfast(a2);
  c = cn;
  h = sigm(a3) * tanhfast(cn);
}

__device__ __forceinline__ float wredmax(float v){
  #pragma unroll
  for (int o = 32; o > 0; o >>= 1) v = fmaxf(v, __shfl_xor(v, o));
  return v;
}
__device__ __forceinline__ float wredsum(float v){
  #pragma unroll
  for (int o = 32; o > 0; o >>= 1) v += __shfl_xor(v, o);
  return v;
}

// fence-free device-coherent element access (sc0 sc1, no cache maintenance)
__device__ __forceinline__ void ast(float* p, float v){
  __hip_atomic_store(p, v, __ATOMIC_RELAXED, __HIP_MEMORY_SCOPE_AGENT);
}
__device__ __forceinline__ float ald(const float* p){
  return __hip_atomic_load(p, __ATOMIC_RELAXED, __HIP_MEMORY_SCOPE_AGENT);
}

// ---------------- dtype probe ----------------
__global__ void probe_kernel(const unsigned short* __restrict__ w, int* __restrict__ flag)
{
  int cnt = 0;
  for (int i = threadIdx.x; i < 4096; i += 64) {
    unsigned e = (w[i] >> 7) & 0xFFu;
    if (e >= 0xC0u) cnt++;
  }
  #pragma unroll
  for (int o = 32; o > 0; o >>= 1) cnt += __shfl_xor(cnt, o);
  if (threadIdx.x == 0) *flag = (cnt > 32) ? 1 : 0;
}

__device__ __forceinline__ float load_any(const void* src, int i, int isf32){
  return isf32 ? ((const float*)src)[i]
               : __uint_as_float(((unsigned)((const unsigned short*)src)[i]) << 16);
}

__global__ void conv_kernel(const void* __restrict__ src, float* __restrict__ dst, int n,
                            const int* __restrict__ flagp)
{
  int i = blockIdx.x * 256 + threadIdx.x;
  if (i >= n) return;
  dst[i] = load_any(src, i, *flagp);
}

__global__ void bias_kernel(const void* __restrict__ a, const void* __restrict__ bsrc,
                            float* __restrict__ dst, int n, const int* __restrict__ flagp)
{
  int i = blockIdx.x * 256 + threadIdx.x;
  if (i >= n) return;
  int f = *flagp;
  dst[i] = load_any(a, i, f) + load_any(bsrc, i, f);
}

// Swizzled bf16 weight layout for an (R x K) matrix:
//   swz[ (((R>>6)*(Kt>>3) + (k>>3))*64 + (R&63))*8 + (k&7) ] = bf16(W[r][k])
__global__ void swzb_kernel(const void* __restrict__ src, unsigned short* __restrict__ dst,
                            int R, int Ks, int Kt, int c0, int perm, const int* __restrict__ flagp)
{
  int i = blockIdx.x * 256 + threadIdx.x;
  if (i >= R * Ks) return;
  int r = i / Ks;
  int k = i - r * Ks;
  int kk = k + c0;
  int Rr = r;
  if (perm) {
    int g = r >> 8, j = r & 255;
    Rr = ((j >> 4) << 6) + (g << 4) + (j & 15);
  }
  float v = load_any(src, i, *flagp);
  __hip_bfloat16 bv = __float2bfloat16(v);
  dst[(((size_t)(Rr >> 6) * (size_t)(Kt >> 3) + (size_t)(kk >> 3)) * 64 + (Rr & 63)) * 8 + (kk & 7)] =
      *(unsigned short*)&bv;
}

// one full row r of an (R x K) swizzled bf16 matrix, x in LDS
template<int K>
__device__ __forceinline__ float dot1w(const unsigned short* __restrict__ w, int r,
                                       const float* __restrict__ xs)
{
  constexpr int KC = K >> 3;
  const uint4* __restrict__ p = (const uint4*)w + (size_t)(r >> 6) * KC * 64 + (r & 63);
  float a = 0.0f;
  #pragma unroll 4
  for (int kc = 0; kc < KC; ++kc) {
    const uint4 q = p[(size_t)kc * 64];
    const float4 x0 = *(const float4*)(xs + kc * 8);
    const float4 x1 = *(const float4*)(xs + kc * 8 + 4);
    a += blo(q.x)*x0.x + bhi(q.x)*x0.y + blo(q.y)*x0.z + bhi(q.y)*x0.w
       + blo(q.z)*x1.x + bhi(q.z)*x1.y + blo(q.w)*x1.z + bhi(q.w)*x1.w;
  }
  return a;
}

// Split-K 4-gate partial dot (encoders): rows {g*256+j}, K-slice q.
template<int KC, int SL>
__device__ __forceinline__ void dot4s(const unsigned short* __restrict__ w, int j, int q,
                                      const float* __restrict__ xsl, float out4[4])
{
  const int lane = j & 63, wq = j >> 6;
  const uint4* __restrict__ p0 = (const uint4*)w + ((size_t)(wq     ) * KC + q * SL) * 64 + lane;
  const uint4* __restrict__ p1 = (const uint4*)w + ((size_t)(wq + 4 ) * KC + q * SL) * 64 + lane;
  const uint4* __restrict__ p2 = (const uint4*)w + ((size_t)(wq + 8 ) * KC + q * SL) * 64 + lane;
  const uint4* __restrict__ p3 = (const uint4*)w + ((size_t)(wq + 12) * KC + q * SL) * 64 + lane;
  float a0 = 0.0f, a1 = 0.0f, a2 = 0.0f, a3 = 0.0f;
  #pragma unroll 4
  for (int kc = 0; kc < SL; ++kc) {
    const float4 x0 = *(const float4*)(xsl + kc * 8);
    const float4 x1 = *(const float4*)(xsl + kc * 8 + 4);
    uint4 qq;
    qq = p0[(size_t)kc * 64];
    a0 += blo(qq.x)*x0.x + bhi(qq.x)*x0.y + blo(qq.y)*x0.z + bhi(qq.y)*x0.w
        + blo(qq.z)*x1.x + bhi(qq.z)*x1.y + blo(qq.w)*x1.z + bhi(qq.w)*x1.w;
    qq = p1[(size_t)kc * 64];
    a1 += blo(qq.x)*x0.x + bhi(qq.x)*x0.y + blo(qq.y)*x0.z + bhi(qq.y)*x0.w
        + blo(qq.z)*x1.x + bhi(qq.z)*x1.y + blo(qq.w)*x1.z + bhi(qq.w)*x1.w;
    qq = p2[(size_t)kc * 64];
    a2 += blo(qq.x)*x0.x + bhi(qq.x)*x0.y + blo(qq.y)*x0.z + bhi(qq.y)*x0.w
        + blo(qq.z)*x1.x + bhi(qq.z)*x1.y + blo(qq.w)*x1.z + bhi(qq.w)*x1.w;
    qq = p3[(size_t)kc * 64];
    a3 += blo(qq.x)*x0.x + bhi(qq.x)*x0.y + blo(qq.y)*x0.z + bhi(qq.y)*x0.w
        + blo(qq.z)*x1.x + bhi(qq.z)*x1.y + blo(qq.w)*x1.z + bhi(qq.w)*x1.w;
  }
  out4[0] = a0; out4[1] = a1; out4[2] = a2; out4[3] = a3;
}

// ---------------- encoder (unchanged) ----------------
__global__ __launch_bounds__(1024, 1) void enc0_kernel(
    const int* __restrict__ src, const float* __restrict__ emb_f,
    const unsigned short* __restrict__ wF, const unsigned short* __restrict__ wB,
    const float* __restrict__ bF, const float* __restrict__ bB,
    float* __restrict__ f0, float* __restrict__ b0)
{
  const int blk = blockIdx.x, dir = blk >> 6, b = blk & 63, tid = threadIdx.x;
  const unsigned short* w = dir ? wB : wF;
  const float* bi = dir ? bB : bF;
  float* outp = dir ? b0 : f0;
  __shared__ __align__(16) float xs[512];
  __shared__ __align__(16) float work4[4096];
  const int q = tid >> 8, j = tid & 255;
  float bias_g[4];
  if (tid < 256) {
    #pragma unroll
    for (int g = 0; g < 4; ++g) bias_g[g] = bi[g * 256 + tid];
    xs[256 + tid] = 0.0f;
  }
  float c = 0.0f, h = 0.0f;
  const size_t bS = (size_t)b * S_;
  for (int t = 0; t < S_; ++t) {
    const int tp = dir ? (S_ - 1 - t) : t;
    const int tok = src[bS + tp];
    if (tid < 256) xs[tid] = emb_f[(size_t)tok * D_ + tid];
    __syncthreads();
    float o4[4];
    dot4s<64, 16>(w, j, q, xs + q * 128, o4);
    #pragma unroll
    for (int g = 0; g < 4; ++g) work4[(g * 4 + q) * 256 + j] = o4[g];
    __syncthreads();
    if (tid < 256) {
      float gv[4];
      #pragma unroll
      for (int g = 0; g < 4; ++g)
        gv[g] = work4[(g*4+0)*256 + tid] + work4[(g*4+1)*256 + tid]
              + work4[(g*4+2)*256 + tid] + work4[(g*4+3)*256 + tid] + bias_g[g];
      cellupd(gv[0], gv[1], gv[2], gv[3], c, h);
      xs[256 + tid] = h;
      outp[(bS + tp) * H_ + tid] = h;
    }
    __syncthreads();
  }
}

__global__ __launch_bounds__(1024, 1) void enc1_kernel(
    const float* __restrict__ f0, const float* __restrict__ b0,
    const unsigned short* __restrict__ wF, const unsigned short* __restrict__ wB,
    const float* __restrict__ bF, const float* __restrict__ bB,
    float* __restrict__ enc_out, float* __restrict__ hcbuf)
{
  const int blk = blockIdx.x, dir = blk >> 6, b = blk & 63, tid = threadIdx.x;
  const unsigned short* w = dir ? wB : wF;
  const float* bi = dir ? bB : bF;
  __shared__ __align__(16) float xs[768];
  __shared__ __align__(16) float work4[4096];
  const int q = tid >> 8, j = tid & 255;
  float bias_g[4];
  if (tid < 256) {
    #pragma unroll
    for (int g = 0; g < 4; ++g) bias_g[g] = bi[g * 256 + tid];
    xs[512 + tid] = 0.0f;
  }
  float c = 0.0f, h = 0.0f;
  const size_t bS = (size_t)b * S_;
  for (int t = 0; t < S_; ++t) {
    const int tp = dir ? (S_ - 1 - t) : t;
    const size_t row = (bS + tp) * (size_t)H_;
    if (tid < 512) {
      const int jj = tid & 255;
      xs[tid] = (tid < 256) ? f0[row + jj] : b0[row + jj];
    }
    __syncthreads();
    float o4[4];
    dot4s<96, 24>(w, j, q, xs + q * 192, o4);
    #pragma unroll
    for (int g = 0; g < 4; ++g) work4[(g * 4 + q) * 256 + j] = o4[g];
    __syncthreads();
    if (tid < 256) {
      float gv[4];
      #pragma unroll
      for (int g = 0; g < 4; ++g)
        gv[g] = work4[(g*4+0)*256 + tid] + work4[(g*4+1)*256 + tid]
              + work4[(g*4+2)*256 + tid] + work4[(g*4+3)*256 + tid] + bias_g[g];
      cellupd(gv[0], gv[1], gv[2], gv[3], c, h);
      xs[512 + tid] = h;
      enc_out[(bS + tp) * 512 + dir * 256 + tid] = h;
    }
    __syncthreads();
  }
  if (tid < 256) {
    const int BH = B_ * H_;
    float* hout = hcbuf + (dir ? 2 * BH : 0);
    hout[(size_t)b * H_ + tid]      = h;
    hout[BH + (size_t)b * H_ + tid] = c;
  }
}

// proj (unchanged)
__global__ __launch_bounds__(256) void proj_kernel(
    const float* __restrict__ enc_out, const float* __restrict__ hcbuf,
    const unsigned short* __restrict__ wenc_s,
    const unsigned short* __restrict__ hpw_s, const unsigned short* __restrict__ cpw_s,
    const float* __restrict__ hpb_f, const float* __restrict__ cpb_f,
    float* __restrict__ epT, float* __restrict__ h0c0)
{
  __shared__ __align__(16) float xs[16 * 512];
  const int blk = blockIdx.x, tid = threadIdx.x;
  if (blk < 1024) {
    const int b = blk >> 4, s0 = (blk & 15) * 16;
    const float* srcp = enc_out + ((size_t)b * S_ + s0) * 512;
    for (int i = tid; i < 16 * 512; i += 256) xs[i] = srcp[i];
    __syncthreads();
    float acc[16];
    #pragma unroll
    for (int r = 0; r < 16; ++r) acc[r] = 0.0f;
    const uint4* p = (const uint4*)wenc_s + (size_t)(tid >> 6) * 64 * 64 + (tid & 63);
    for (int kc = 0; kc < 64; ++kc) {
      const uint4 q = p[(size_t)kc * 64];
      const float w0=blo(q.x), w1=bhi(q.x), w2=blo(q.y), w3=bhi(q.y),
                  w4=blo(q.z), w5=bhi(q.z), w6=blo(q.w), w7=bhi(q.w);
      #pragma unroll
      for (int r = 0; r < 16; ++r) {
        const float4 x0 = *(const float4*)(xs + r * 512 + kc * 8);
        const float4 x1 = *(const float4*)(xs + r * 512 + kc * 8 + 4);
        acc[r] += w0*x0.x + w1*x0.y + w2*x0.z + w3*x0.w + w4*x1.x + w5*x1.y + w6*x1.z + w7*x1.w;
      }
    }
    float* dst = epT + ((size_t)b * S_ + (size_t)tid) * 256 + s0;
    #pragma unroll
    for (int r = 0; r < 16; ++r) dst[r] = acc[r];
  } else {
    const int b = blk - 1024;
    const int BH = B_ * H_;
    xs[tid]        = hcbuf[(size_t)b * H_ + tid];
    xs[256 + tid]  = hcbuf[2 * BH + (size_t)b * H_ + tid];
    xs[512 + tid]  = hcbuf[BH + (size_t)b * H_ + tid];
    xs[768 + tid]  = hcbuf[3 * BH + (size_t)b * H_ + tid];
    __syncthreads();
    const float hv = dot1w<512>(hpw_s, tid, xs)       + hpb_f[tid];
    const float cv = dot1w<512>(cpw_s, tid, xs + 512) + cpb_f[tid];
    h0c0[(size_t)b * H_ + tid]              = tanhfast(hv);
    h0c0[(size_t)BH + (size_t)b * H_ + tid] = tanhfast(cv);
  }
}

// ---------------- gemb: precompute Wih[:, :256] @ emb[tok] for all 1000 tokens ----------------
__global__ __launch_bounds__(256) void gemb_kernel(
    const float* __restrict__ emb_f, const unsigned short* __restrict__ d0p,
    float* __restrict__ gemb)
{
  __shared__ __align__(16) float xs[16 * 256];
  const int blk = blockIdx.x, tg = blk >> 2, cg = blk & 3, tid = threadIdx.x;
  for (int i = tid; i < 16 * 256; i += 256) {
    const int tk = tg * 16 + (i >> 8);
    xs[i] = (tk < V_) ? emb_f[(size_t)tk * 256 + (i & 255)] : 0.0f;
  }
  __syncthreads();
  const int r = cg * 256 + tid;   // gate-row 0..1023
  const uint4* p = (const uint4*)d0p + (size_t)(r >> 6) * 128 * 64 + (r & 63);
  float acc[16];
  #pragma unroll
  for (int ti = 0; ti < 16; ++ti) acc[ti] = 0.0f;
  for (int kc = 0; kc < 32; ++kc) {
    const uint4 q = p[(size_t)kc * 64];
    const float w0=blo(q.x), w1=bhi(q.x), w2=blo(q.y), w3=bhi(q.y),
                w4=blo(q.z), w5=bhi(q.z), w6=blo(q.w), w7=bhi(q.w);
    #pragma unroll
    for (int ti = 0; ti < 16; ++ti) {
      const float4 x0 = *(const float4*)(xs + ti * 256 + kc * 8);
      const float4 x1 = *(const float4*)(xs + ti * 256 + kc * 8 + 4);
      acc[ti] += w0*x0.x + w1*x0.y + w2*x0.z + w3*x0.w + w4*x1.x + w5*x1.y + w6*x1.z + w7*x1.w;
    }
  }
  #pragma unroll
  for (int ti = 0; ti < 16; ++ti) {
    const int tk = tg * 16 + ti;
    if (tk < V_) gemb[(size_t)tk * 1024 + r] = acc[ti];
  }
}

__global__ void zero_cnt_kernel(int* __restrict__ cnt)
{
  for (int i = threadIdx.x; i < 2048; i += 256) cnt[i] = 0;
}

// ---------------- fused decoder v6: 256 blocks, Bk = b*4 + k ----------------
// v5 (weights L2-resident) + padded barrier counters (128B apart, no false sharing) +
// split ARRIVE/WAIT barriers with local-K compute overlapped under sync latency:
//   sync1 gap: cell0 gates, hl0_prev K-part (local)   sync2 gap: cell1 gates, hl1_prev K-part
__global__ __launch_bounds__(1024, 1) void dec_fused_kernel(
    const int* __restrict__ src, const int* __restrict__ tgt,
    const float* __restrict__ h0c0,
    const float* __restrict__ epT, const float* __restrict__ enc_out,
    const float* __restrict__ gemb,
    const unsigned short* __restrict__ wdec_s,
    const unsigned short* __restrict__ d0p, const unsigned short* __restrict__ d1p,
    const float* __restrict__ d0b, const float* __restrict__ d1b,
    const float* __restrict__ attv_f,
    float* __restrict__ dec_h,
    float* __restrict__ esc, float* __restrict__ ctxg,
    float* __restrict__ hl0g, float* __restrict__ hl1g,
    int* __restrict__ cnt)
{
  const int Bk = blockIdx.x, b = Bk >> 2, k = Bk & 3, tid = threadIdx.x;
  const int j64 = k * 64;

  __shared__ __align__(16) float epl[256 * 65];            // epT[s][j-slice], pitch 65
  __shared__ __align__(16) unsigned short eol[128 * 264];  // enc_out[d-slice][s], bf16
  __shared__ __align__(16) float work[1024];               // cell0 gate partials (E1+E2)
  __shared__ __align__(16) float workF[1024];              // D scratch, then cell1 partials (F1+F2)
  __shared__ __align__(16) float xs0[768];        // [ctx(512) | hl0_prev(256)]
  __shared__ __align__(16) float hl1s[256];
  __shared__ __align__(16) float hl0n[256];
  __shared__ __align__(16) float qloc[64];
  __shared__ __align__(16) float vv[64];
  __shared__ __align__(16) float msk[256];
  __shared__ __align__(16) float wsm[256];
  __shared__ __align__(16) float cl0s[64];
  __shared__ __align__(16) float cl1s[64];
  __shared__ float red[16];

  const float* epb = epT + (size_t)b * (S_ * 256);
  const float* eob = enc_out + (size_t)b * (S_ * 512);

  // ---- prologue: stage slices into LDS (one-time) ----
  for (int i = tid; i < 256 * 64; i += 1024) {
    const int s = i & 255, jj = i >> 8;
    epl[s * 65 + jj] = epb[(size_t)(j64 + jj) * 256 + s];
  }
  for (int i = tid; i < 128 * 256; i += 1024) {
    const int dl = i & 127, s = i >> 7;
    __hip_bfloat16 bv = __float2bfloat16(eob[(size_t)s * 512 + k * 128 + dl]);
    eol[dl * 264 + s] = *(unsigned short*)&bv;
  }
  if (tid < 256) {
    msk[tid] = (src[b * 256 + tid] == 0) ? -1e30f : 0.0f;
    const float h0 = h0c0[b * 256 + tid];
    hl1s[tid] = h0;
    xs0[512 + tid] = h0;
  }
  float b0r[4], b1r[4];
  if (tid < 64) {
    vv[tid] = attv_f[j64 + tid];
    const float c0 = h0c0[B_ * H_ + b * 256 + j64 + tid];
    cl0s[tid] = c0; cl1s[tid] = c0;
    #pragma unroll
    for (int g = 0; g < 4; ++g) {
      b0r[g] = d0b[g * 256 + j64 + tid];
      b1r[g] = d1b[g * 256 + j64 + tid];
    }
  }
  __syncthreads();

  int syncno = 0;
  // split barrier among the 4 blocks of batch b; counter padded to its own 128B line
#define ARRIVE() do {                                                                    \
    ++syncno;                                                                            \
    __syncthreads();  /* drains vmcnt(0): all sc1 data stores acked at coherence pt */   \
    if (tid == 0)                                                                        \
      __hip_atomic_fetch_add(&cnt[b * 32], 1, __ATOMIC_RELAXED, __HIP_MEMORY_SCOPE_AGENT); \
  } while (0)
#define WAIT() do {                                                                      \
    if (tid == 0) {                                                                      \
      while (__hip_atomic_load(&cnt[b * 32], __ATOMIC_RELAXED, __HIP_MEMORY_SCOPE_AGENT) \
             < 4 * syncno)                                                               \
        __builtin_amdgcn_s_sleep(1);                                                     \
    }                                                                                    \
    __syncthreads();                                                                     \
    asm volatile("" ::: "memory");                                                       \
  } while (0)

  const int lr = tid & 255, q4 = tid >> 8;
  const int gg4 = lr >> 6, jj4 = lr & 63;
  const uint4* __restrict__ d0pb = (const uint4*)d0p + (size_t)(gg4 * 4 + k) * 128 * 64 + jj4;
  const uint4* __restrict__ d1pb = (const uint4*)d1p + (size_t)(gg4 * 4 + k) * 64 * 64 + jj4;

  for (int t = 0; t < T_; ++t) {
    // prefetch the token gate-table slice (consumed at cell0, hides L2/L3 latency)
    float gpre[4];
    if (tid < 64) {
      const float* ge = gemb + (size_t)tgt[b * 257 + t] * 1024;
      #pragma unroll
      for (int g = 0; g < 4; ++g) gpre[g] = ge[g * 256 + j64 + tid];
    }

    // ---- A: qloc = Wdec[j-slice] @ hl1s ----
    {
      const int jj = tid & 63, q16 = tid >> 6;
      const uint4* p = (const uint4*)wdec_s + ((size_t)k * 32 + q16 * 2) * 64 + jj;
      const float* xsl = hl1s + q16 * 16;
      const uint4 w0 = p[0], w1 = p[64];
      const float4 xa = *(const float4*)(xsl);
      const float4 xb = *(const float4*)(xsl + 4);
      const float4 xc = *(const float4*)(xsl + 8);
      const float4 xd = *(const float4*)(xsl + 12);
      const float a =
          blo(w0.x)*xa.x + bhi(w0.x)*xa.y + blo(w0.y)*xa.z + bhi(w0.y)*xa.w
        + blo(w0.z)*xb.x + bhi(w0.z)*xb.y + blo(w0.w)*xb.z + bhi(w0.w)*xb.w
        + blo(w1.x)*xc.x + bhi(w1.x)*xc.y + blo(w1.y)*xc.z + bhi(w1.y)*xc.w
        + blo(w1.z)*xd.x + bhi(w1.z)*xd.y + blo(w1.w)*xd.z + bhi(w1.w)*xd.w;
      work[q16 * 64 + jj] = a;
    }
    __syncthreads();
    if (tid < 64) {
      float q = 0.0f;
      #pragma unroll
      for (int i = 0; i < 16; ++i) q += work[i * 64 + tid];
      qloc[tid] = q;
    }
    __syncthreads();

    // ---- B: partial energies over this block's j-slice for ALL 256 s ----
    {
      const int s = tid & 255, jq = tid >> 8;
      const float* ep = epl + s * 65 + jq * 16;
      const float* qv = qloc + jq * 16;
      const float* vp = vv + jq * 16;
      float a = 0.0f;
      #pragma unroll
      for (int i = 0; i < 16; ++i)
        a += vp[i] * tanhfast(ep[i] + qv[i]);
      work[jq * 256 + s] = a;
    }
    __syncthreads();
    if (tid < 256)
      ast(&esc[b * 1024 + k * 256 + tid],
          work[tid] + work[256 + tid] + work[512 + tid] + work[768 + tid]);
    ARRIVE();  // sync1 arrive: energy partials posted

    // ---- E1 (overlap): cell0 gate partials, hl0_prev K-cols 768..1023 (local) ----
    {
      const uint4* p = d0pb + (size_t)(96 + q4 * 8) * 64;
      const float* xsl = xs0 + 512 + q4 * 64;
      float a = 0.0f;
      #pragma unroll
      for (int kc = 0; kc < 8; ++kc) {
        const uint4 w = p[(size_t)kc * 64];
        const float4 x0 = *(const float4*)(xsl + kc * 8);
        const float4 x1 = *(const float4*)(xsl + kc * 8 + 4);
        a += blo(w.x)*x0.x + bhi(w.x)*x0.y + blo(w.y)*x0.z + bhi(w.y)*x0.w
           + blo(w.z)*x1.x + bhi(w.z)*x1.y + blo(w.w)*x1.z + bhi(w.w)*x1.w;
      }
      work[q4 * 256 + lr] = a;
    }
    WAIT();    // sync1 wait: all energy partials visible

    // ---- C (replicated): sum partials + softmax ----
    {
      float e = -1e30f;
      if (tid < 256) {
        const float* eb = esc + b * 1024;
        e = ald(&eb[tid]) + ald(&eb[256 + tid]) + ald(&eb[512 + tid]) + ald(&eb[768 + tid])
          + msk[tid];
      }
      const float m0 = wredmax(e);
      if (tid < 256 && (tid & 63) == 0) red[tid >> 6] = m0;
      __syncthreads();
      const float m = fmaxf(fmaxf(red[0], red[1]), fmaxf(red[2], red[3]));
      const float pe = (tid < 256) ? __expf(e - m) : 0.0f;
      const float ss = wredsum(pe);
      if (tid < 256 && (tid & 63) == 0) red[4 + (tid >> 6)] = ss;
      __syncthreads();
      const float inv = 1.0f / ((red[4] + red[5]) + (red[6] + red[7]));
      if (tid < 256) wsm[tid] = pe * inv;
    }
    __syncthreads();

    // ---- D: ctx d-slice [128k, 128k+128) from LDS enc_out slice (scratch: workF) ----
    {
      const int dq = tid & 127, sg = tid >> 7;    // 8 s-groups x 128 d
      const uint4* er = (const uint4*)(eol + dq * 264 + sg * 32);
      const float* wp = wsm + sg * 32;
      float a = 0.0f;
      #pragma unroll
      for (int i4 = 0; i4 < 4; ++i4) {
        const uint4 q = er[i4];
        const float* w8 = wp + i4 * 8;
        a += blo(q.x)*w8[0] + bhi(q.x)*w8[1] + blo(q.y)*w8[2] + bhi(q.y)*w8[3]
           + blo(q.z)*w8[4] + bhi(q.z)*w8[5] + blo(q.w)*w8[6] + bhi(q.w)*w8[7];
      }
      workF[sg * 128 + dq] = a;
    }
    __syncthreads();
    if (tid < 128) {
      float a = 0.0f;
      #pragma unroll
      for (int g = 0; g < 8; ++g) a += workF[g * 128 + tid];
      ast(&ctxg[b * 512 + k * 128 + tid], a);
    }
    ARRIVE();  // sync2 arrive: ctx slice posted

    // ---- F1 (overlap): cell1 gate partials, hl1_prev K-cols 256..511 (local) ----
    {
      const uint4* p = d1pb + (size_t)(32 + q4 * 8) * 64;
      const float* xsl = hl1s + q4 * 64;
      float a = 0.0f;
      #pragma unroll
      for (int kc = 0; kc < 8; ++kc) {
        const uint4 w = p[(size_t)kc * 64];
        const float4 x0 = *(const float4*)(xsl + kc * 8);
        const float4 x1 = *(const float4*)(xsl + kc * 8 + 4);
        a += blo(w.x)*x0.x + bhi(w.x)*x0.y + blo(w.y)*x0.z + bhi(w.y)*x0.w
           + blo(w.z)*x1.x + bhi(w.z)*x1.y + blo(w.w)*x1.z + bhi(w.w)*x1.w;
      }
      workF[q4 * 256 + lr] = a;
    }
    WAIT();    // sync2 wait: full ctx visible
    if (tid < 512) xs0[tid] = ald(&ctxg[b * 512 + tid]);
    __syncthreads();

    // ---- E2: cell0 gate partials, ctx K-cols 256..767, accumulate into work ----
    {
      const uint4* p = d0pb + (size_t)(32 + q4 * 16) * 64;
      const float* xsl = xs0 + q4 * 128;
      float a = 0.0f;
      #pragma unroll 8
      for (int kc = 0; kc < 16; ++kc) {
        const uint4 w = p[(size_t)kc * 64];
        const float4 x0 = *(const float4*)(xsl + kc * 8);
        const float4 x1 = *(const float4*)(xsl + kc * 8 + 4);
        a += blo(w.x)*x0.x + bhi(w.x)*x0.y + blo(w.y)*x0.z + bhi(w.y)*x0.w
           + blo(w.z)*x1.x + bhi(w.z)*x1.y + blo(w.w)*x1.z + bhi(w.w)*x1.w;
      }
      work[q4 * 256 + lr] += a;
    }
    __syncthreads();
    if (tid < 64) {
      float gv[4];
      #pragma unroll
      for (int g = 0; g < 4; ++g) {
        const int r = g * 64 + tid;
        gv[g] = work[r] + work[256 + r] + work[512 + r] + work[768 + r]
              + b0r[g] + gpre[g];
      }
      float c = cl0s[tid], h;
      cellupd(gv[0], gv[1], gv[2], gv[3], c, h);
      cl0s[tid] = c;
      ast(&hl0g[b * 256 + j64 + tid], h);
    }
    ARRIVE();  // sync3 arrive: hl0 slice posted
    WAIT();    // sync3 wait: full hl0(t) visible
    if (tid < 256) {
      const float hv = ald(&hl0g[b * 256 + tid]);
      hl0n[tid] = hv;
      xs0[512 + tid] = hv;   // becomes hl0_prev for next step's E1
    }
    __syncthreads();

    // ---- F2: cell1 gate partials, hl0 K-cols 0..255, accumulate into workF ----
    {
      const uint4* p = d1pb + (size_t)(q4 * 8) * 64;
      const float* xsl = hl0n + q4 * 64;
      float a = 0.0f;
      #pragma unroll
      for (int kc = 0; kc < 8; ++kc) {
        const uint4 w = p[(size_t)kc * 64];
        const float4 x0 = *(const float4*)(xsl + kc * 8);
        const float4 x1 = *(const float4*)(xsl + kc * 8 + 4);
        a += blo(w.x)*x0.x + bhi(w.x)*x0.y + blo(w.y)*x0.z + bhi(w.y)*x0.w
           + blo(w.z)*x1.x + bhi(w.z)*x1.y + blo(w.w)*x1.z + bhi(w.w)*x1.w;
      }
      workF[q4 * 256 + lr] += a;
    }
    __syncthreads();
    if (tid < 64) {
      float gv[4];
      #pragma unroll
      for (int g = 0; g < 4; ++g) {
        const int r = g * 64 + tid;
        gv[g] = workF[r] + workF[256 + r] + workF[512 + r] + workF[768 + r] + b1r[g];
      }
      float c = cl1s[tid], h;
      cellupd(gv[0], gv[1], gv[2], gv[3], c, h);
      cl1s[tid] = c;
      ast(&hl1g[b * 256 + j64 + tid], h);
      dec_h[((size_t)b * T_ + t) * H_ + j64 + tid] = h;
    }
    ARRIVE();  // sync4 arrive: hl1 slice posted
    WAIT();    // sync4 wait: full hl1(t) visible
    if (tid < 256) hl1s[tid] = ald(&hl1g[b * 256 + tid]);
    __syncthreads();
  }
#undef ARRIVE
#undef WAIT
}

// out (unchanged)
__global__ __launch_bounds__(256) void out_kernel(
    const float* __restrict__ dec_h, const unsigned short* __restrict__ emb_s,
    void* __restrict__ out, const int* __restrict__ flagp)
{
  __shared__ __align__(16) float hs[16 * 256];
  const int blk = blockIdx.x, tid = threadIdx.x;
  const int isf32 = *flagp;
  const float* srcp = dec_h + (size_t)blk * (16 * 256);
  for (int i = tid; i < 16 * 256; i += 256) hs[i] = srcp[i];
  __syncthreads();
  #pragma unroll
  for (int vi = 0; vi < 4; ++vi) {
    const int v = tid + vi * 256;
    if (v < V_) {
      const uint4* p = (const uint4*)emb_s + (size_t)(v >> 6) * 32 * 64 + (v & 63);
      float acc[16];
      #pragma unroll
      for (int r = 0; r < 16; ++r) acc[r] = 0.0f;
      for (int kc = 0; kc < 32; ++kc) {
        const uint4 q = p[(size_t)kc * 64];
        const float w0=blo(q.x), w1=bhi(q.x), w2=blo(q.y), w3=bhi(q.y),
                    w4=blo(q.z), w5=bhi(q.z), w6=blo(q.w), w7=bhi(q.w);
        #pragma unroll
        for (int r = 0; r < 16; ++r) {
          const float4 x0 = *(const float4*)(hs + r * 256 + kc * 8);
          const float4 x1 = *(const float4*)(hs + r * 256 + kc * 8 + 4);
          acc[r] += w0*x0.x + w1*x0.y + w2*x0.z + w3*x0.w + w4*x1.x + w5*x1.y + w6*x1.z + w7*x1.w;
        }
      }
      const size_t rowbase = (size_t)blk * 16;
      if (isf32) {
        float* o = (float*)out;
        #pragma unroll
        for (int r = 0; r < 16; ++r) o[(rowbase + r) * V_ + v] = acc[r];
      } else {
        __hip_bfloat16* o = (__hip_bfloat16*)out;
        #pragma unroll
        for (int r = 0; r < 16; ++r) o[(rowbase + r) * V_ + v] = __float2bfloat16(acc[r]);
      }
    }
  }
}

extern "C" void kernel_launch(void* const* d_in, const int* in_sizes, int n_in,
                              void* d_out, int out_size, void* d_ws, size_t ws_size,
                              hipStream_t stream)
{
  (void)in_sizes; (void)n_in; (void)out_size; (void)ws_size;
  const int* src = (const int*)d_in[0];
  const int* tgt = (const int*)d_in[1];

  char* base = (char*)d_ws;
  int* flag = (int*)base;
  float* ws = (float*)(base + 256);
  size_t off = 0;
  float* f0      = ws + off; off += (size_t)B_ * S_ * H_;
  float* b0      = ws + off; off += (size_t)B_ * S_ * H_;
  float* enc_out = ws + off; off += (size_t)B_ * S_ * 2 * H_;
  float* hcbuf   = ws + off; off += 4 * (size_t)B_ * H_;
  float* h0c0    = ws + off; off += 2 * (size_t)B_ * H_;
  float* emb_f   = ws + off; off += (size_t)V_ * D_;
  float* gemb    = ws + off; off += (size_t)V_ * 1024;
  float* esc     = ws + off; off += (size_t)B_ * S_ * 4;
  float* ctxg    = ws + off; off += (size_t)B_ * 512;
  float* hl0g    = ws + off; off += (size_t)B_ * H_;
  float* hl1g    = ws + off; off += (size_t)B_ * H_;
  int*   cntp    = (int*)(ws + off); off += 2048;
  float* e0f_b   = ws + off; off += 1024;
  float* e0b_b   = ws + off; off += 1024;
  float* e1f_b   = ws + off; off += 1024;
  float* e1b_b   = ws + off; off += 1024;
  float* d0_b    = ws + off; off += 1024;
  float* d1_b    = ws + off; off += 1024;
  float* hpb_f   = ws + off; off += 256;
  float* cpb_f   = ws + off; off += 256;
  float* attv_f  = ws + off; off += 256;
  unsigned short* us = (unsigned short*)(ws + off);
  size_t uo = 0;
  unsigned short* e0f_s  = us + uo; uo += (size_t)1024 * 512;
  unsigned short* e0b_s  = us + uo; uo += (size_t)1024 * 512;
  unsigned short* e1f_s  = us + uo; uo += (size_t)1024 * 768;
  unsigned short* e1b_s  = us + uo; uo += (size_t)1024 * 768;
  unsigned short* d0p_s  = us + uo; uo += (size_t)1024 * 1024;
  unsigned short* d1p_s  = us + uo; uo += (size_t)1024 * 512;
  unsigned short* wdec_s = us + uo; uo += (size_t)256 * 256;
  unsigned short* wenc_s = us + uo; uo += (size_t)256 * 512;
  unsigned short* hpw_s  = us + uo; uo += (size_t)256 * 512;
  unsigned short* cpw_s  = us + uo; uo += (size_t)256 * 512;
  unsigned short* emb_s  = us + uo; uo += (size_t)1024 * 256;
  float* dec_h = f0;
  float* epT   = b0;

  hipLaunchKernelGGL(probe_kernel, dim3(1), dim3(64), 0, stream,
                     (const unsigned short*)d_in[3], flag);

  auto swz = [&](int idx, unsigned short* dst, int R, int Ks, int Kt, int c0, int perm){
    const int n = R * Ks;
    hipLaunchKernelGGL(swzb_kernel, dim3((n + 255) / 256), dim3(256), 0, stream,
                       d_in[idx], dst, R, Ks, Kt, c0, perm, flag);
  };
  auto bias2 = [&](int ia, int ib, float* dst, int n){
    hipLaunchKernelGGL(bias_kernel, dim3((n + 255) / 256), dim3(256), 0, stream,
                       d_in[ia], d_in[ib], dst, n, flag);
  };

  hipLaunchKernelGGL(conv_kernel, dim3((V_ * D_ + 255) / 256), dim3(256), 0, stream,
                     d_in[2], emb_f, V_ * D_, flag);
  hipLaunchKernelGGL(conv_kernel, dim3(1), dim3(256), 0, stream, d_in[28], hpb_f, 256, flag);
  hipLaunchKernelGGL(conv_kernel, dim3(1), dim3(256), 0, stream, d_in[30], cpb_f, 256, flag);
  hipLaunchKernelGGL(conv_kernel, dim3(1), dim3(256), 0, stream, d_in[33], attv_f, 256, flag);
  bias2(5, 6, e0f_b, 1024);   bias2(9, 10, e0b_b, 1024);
  bias2(13, 14, e1f_b, 1024); bias2(17, 18, e1b_b, 1024);
  bias2(21, 22, d0_b, 1024);  bias2(25, 26, d1_b, 1024);
  swz(3,  e0f_s, 1024, 256, 512, 0, 0);   swz(4,  e0f_s, 1024, 256, 512, 256, 0);
  swz(7,  e0b_s, 1024, 256, 512, 0, 0);   swz(8,  e0b_s, 1024, 256, 512, 256, 0);
  swz(11, e1f_s, 1024, 512, 768, 0, 0);   swz(12, e1f_s, 1024, 256, 768, 512, 0);
  swz(15, e1b_s, 1024, 512, 768, 0, 0);   swz(16, e1b_s, 1024, 256, 768, 512, 0);
  swz(19, d0p_s, 1024, 768, 1024, 0, 0);  swz(20, d0p_s, 1024, 256, 1024, 768, 0);
  swz(23, d1p_s, 1024, 256, 512, 0, 0);   swz(24, d1p_s, 1024, 256, 512, 256, 0);
  swz(32, wdec_s, 256, 256, 256, 0, 0);
  swz(31, wenc_s, 256, 512, 512, 0, 0);
  swz(27, hpw_s, 256, 512, 512, 0, 0);
  swz(29, cpw_s, 256, 512, 512, 0, 0);
  swz(2,  emb_s, 1000, 256, 256, 0, 0);

  // token-gate table (needs emb_f + d0p_s)
  hipLaunchKernelGGL(gemb_kernel, dim3(252), dim3(256), 0, stream, emb_f, d0p_s, gemb);

  hipLaunchKernelGGL(enc0_kernel, dim3(128), dim3(1024), 0, stream,
                     src, emb_f, e0f_s, e0b_s, e0f_b, e0b_b, f0, b0);
  hipLaunchKernelGGL(enc1_kernel, dim3(128), dim3(1024), 0, stream,
                     f0, b0, e1f_s, e1b_s, e1f_b, e1b_b, enc_out, hcbuf);
  hipLaunchKernelGGL(proj_kernel, dim3(1088), dim3(256), 0, stream,
                     enc_out, hcbuf, wenc_s, hpw_s, cpw_s, hpb_f, cpb_f, epT, h0c0);

  hipLaunchKernelGGL(zero_cnt_kernel, dim3(1), dim3(256), 0, stream, cntp);

  {
    const int* srcp_ = src; const int* tgtp_ = tgt;
    const float* h0c0_ = h0c0; const float* epT_ = epT; const float* eo_ = enc_out;
    const float* gemb_ = gemb;
    const unsigned short* wdec_ = wdec_s;
    const unsigned short* d0p_ = d0p_s; const unsigned short* d1p_ = d1p_s;
    const float* d0b_ = d0_b; const float* d1b_ = d1_b; const float* attv_ = attv_f;
    float* dech_ = dec_h; float* esc_ = esc; float* ctxg_ = ctxg;
    float* hl0g_ = hl0g; float* hl1g_ = hl1g; int* cnt_ = cntp;
    void* kargs[] = {
      (void*)&srcp_, (void*)&tgtp_, (void*)&h0c0_, (void*)&epT_, (void*)&eo_,
      (void*)&gemb_, (void*)&wdec_, (void*)&d0p_, (void*)&d1p_,
      (void*)&d0b_, (void*)&d1b_, (void*)&attv_,
      (void*)&dech_, (void*)&esc_, (void*)&ctxg_, (void*)&hl0g_, (void*)&hl1g_, (void*)&cnt_
    };
    hipError_t e = hipLaunchCooperativeKernel((const void*)dec_fused_kernel,
                                              dim3(256), dim3(1024), kargs, 0, stream);
    if (e != hipSuccess) {
      // fallback: plain launch (256 blocks, 1 block/CU, all co-resident)
      hipLaunchKernelGGL(dec_fused_kernel, dim3(256), dim3(1024), 0, stream,
                         srcp_, tgtp_, h0c0_, epT_, eo_, gemb_, wdec_, d0p_, d1p_,
                         d0b_, d1b_, attv_, dech_, esc_, ctxg_, hl0g_, hl1g_, cnt_);
    }
  }

  hipLaunchKernelGGL(out_kernel, dim3(1024), dim3(256), 0, stream,
                     dec_h, emb_s, d_out, flag);
}